// Round 4
// baseline (620.482 us; speedup 1.0000x reference)
//
#include <hip/hip_runtime.h>

#define F 96
#define SCAN_B 1024
#define CHUNKS 8
#define CW 12  // F / CHUNKS

typedef float f32x4 __attribute__((ext_vector_type(4)));

// Wt[c][k] stored XOR-swizzled so column-of-W reads spread across bank slots.
#define WT_IDX(c, k) ((c) * 96 + (((k) ^ (((c) & 7) << 2))))

// ================= CSR build =================

__global__ void k_zero_i(int* __restrict__ p, int n) {
    int i = blockIdx.x * blockDim.x + threadIdx.x;
    if (i < n) p[i] = 0;
}

__global__ void k_hist(const int* __restrict__ dst, int* __restrict__ hist, int E) {
    int e = blockIdx.x * blockDim.x + threadIdx.x;
    if (e < E) atomicAdd(&hist[dst[e]], 1);
}

__global__ void k_dinv(const int* __restrict__ hist, float* __restrict__ dinv, int N) {
    int i = blockIdx.x * blockDim.x + threadIdx.x;
    if (i < N) dinv[i] = rsqrtf((float)hist[i] + 1.0f);  // +1 self-loop
}

__global__ __launch_bounds__(SCAN_B) void k_scan1(const int* __restrict__ hist,
                                                  int* __restrict__ incl,
                                                  int* __restrict__ bsum, int N) {
    __shared__ int s[SCAN_B];
    int i = blockIdx.x * SCAN_B + threadIdx.x;
    int v = (i < N) ? hist[i] : 0;
    s[threadIdx.x] = v;
    __syncthreads();
    for (int off = 1; off < SCAN_B; off <<= 1) {
        int add = (threadIdx.x >= off) ? s[threadIdx.x - off] : 0;
        __syncthreads();
        s[threadIdx.x] += add;
        __syncthreads();
    }
    if (i < N) incl[i] = s[threadIdx.x];
    if (threadIdx.x == SCAN_B - 1) bsum[blockIdx.x] = s[SCAN_B - 1];
}

__global__ __launch_bounds__(SCAN_B) void k_scan2(int* __restrict__ bsum, int nb) {
    __shared__ int s[SCAN_B];
    int v = (threadIdx.x < nb) ? bsum[threadIdx.x] : 0;
    s[threadIdx.x] = v;
    __syncthreads();
    for (int off = 1; off < SCAN_B; off <<= 1) {
        int add = (threadIdx.x >= off) ? s[threadIdx.x - off] : 0;
        __syncthreads();
        s[threadIdx.x] += add;
        __syncthreads();
    }
    if (threadIdx.x < nb) bsum[threadIdx.x] = s[threadIdx.x] - v;  // exclusive
}

__global__ void k_scan3(const int* __restrict__ incl, const int* __restrict__ hist,
                        const int* __restrict__ bsum, int* __restrict__ row_ptr,
                        int* __restrict__ cursor, int N, int E) {
    int i = blockIdx.x * blockDim.x + threadIdx.x;
    if (i < N) {
        int start = incl[i] - hist[i] + bsum[i / SCAN_B];
        row_ptr[i] = start;
        cursor[i] = start;
    }
    if (i == 0) row_ptr[N] = E;
}

__global__ void k_place(const int* __restrict__ src, const int* __restrict__ dst,
                        int* __restrict__ cursor, int* __restrict__ csr_src, int E) {
    int e = blockIdx.x * blockDim.x + threadIdx.x;
    if (e >= E) return;
    int pos = atomicAdd(&cursor[dst[e]], 1);
    csr_src[pos] = src[e];
}

// ================= dense: H = (relu?)(X) @ W =================
// X row-major [N][96]. Output either row-major or packed chunk-major
// Hc[chunk][node][12] (chunk = col/12).

template <bool RELU_IN, bool CHUNKED>
__global__ __launch_bounds__(256) void k_dense(const float* __restrict__ X,
                                               const float* __restrict__ W,
                                               float* __restrict__ H, int N) {
    __shared__ float Wt[96 * 96];
    __shared__ float Xs[64][96];
    int t = threadIdx.x;
    for (int i = t; i < F * F; i += 256) {
        int k = i / F, c = i % F;
        Wt[WT_IDX(c, k)] = W[i];
    }
    int row0 = blockIdx.x * 64;
    for (int i = t; i < 64 * 24; i += 256) {
        int r = i / 24, c4 = (i % 24) * 4;
        int gr = row0 + r;
        float4 v = make_float4(0.f, 0.f, 0.f, 0.f);
        if (gr < N) {
            v = *reinterpret_cast<const float4*>(X + (size_t)gr * F + c4);
            if (RELU_IN) {
                v.x = fmaxf(v.x, 0.f); v.y = fmaxf(v.y, 0.f);
                v.z = fmaxf(v.z, 0.f); v.w = fmaxf(v.w, 0.f);
            }
        }
        *reinterpret_cast<float4*>(&Xs[r][c4]) = v;
    }
    __syncthreads();

    int c2 = t & 31;
    int rg = t >> 5;
    float acc[8][3];
#pragma unroll
    for (int j = 0; j < 8; ++j) { acc[j][0] = 0.f; acc[j][1] = 0.f; acc[j][2] = 0.f; }

    for (int k4 = 0; k4 < F; k4 += 4) {
        float4 w0 = *reinterpret_cast<const float4*>(&Wt[WT_IDX(c2, k4)]);
        float4 w1 = *reinterpret_cast<const float4*>(&Wt[WT_IDX(c2 + 32, k4)]);
        float4 w2 = *reinterpret_cast<const float4*>(&Wt[WT_IDX(c2 + 64, k4)]);
#pragma unroll
        for (int j = 0; j < 8; ++j) {
            float4 xv = *reinterpret_cast<const float4*>(&Xs[rg + 8 * j][k4]);
            acc[j][0] = fmaf(xv.x, w0.x, acc[j][0]);
            acc[j][1] = fmaf(xv.x, w1.x, acc[j][1]);
            acc[j][2] = fmaf(xv.x, w2.x, acc[j][2]);
            acc[j][0] = fmaf(xv.y, w0.y, acc[j][0]);
            acc[j][1] = fmaf(xv.y, w1.y, acc[j][1]);
            acc[j][2] = fmaf(xv.y, w2.y, acc[j][2]);
            acc[j][0] = fmaf(xv.z, w0.z, acc[j][0]);
            acc[j][1] = fmaf(xv.z, w1.z, acc[j][1]);
            acc[j][2] = fmaf(xv.z, w2.z, acc[j][2]);
            acc[j][0] = fmaf(xv.w, w0.w, acc[j][0]);
            acc[j][1] = fmaf(xv.w, w1.w, acc[j][1]);
            acc[j][2] = fmaf(xv.w, w2.w, acc[j][2]);
        }
    }

    size_t NC = (size_t)N * CW;
#pragma unroll
    for (int j = 0; j < 8; ++j) {
        int gr = row0 + rg + 8 * j;
        if (gr < N) {
            if (CHUNKED) {
#pragma unroll
                for (int m = 0; m < 3; ++m) {
                    int c = c2 + 32 * m;
                    H[(size_t)(c / CW) * NC + (size_t)gr * CW + (c % CW)] = acc[j][m];
                }
            } else {
                float* hp = H + (size_t)gr * F;
                hp[c2]      = acc[j][0];
                hp[c2 + 32] = acc[j][1];
                hp[c2 + 64] = acc[j][2];
            }
        }
    }
}

// ================= gather aggregation (chunk x XCD partitioned) =================
// blockIdx%8 = feature chunk (pins chunk to one XCD via round-robin dispatch),
// one thread per node. Hc packed chunk-major; per-XCD hot set = 2.4 MB Hc chunk
// + 200 KB dinv -> L2-resident. O written row-major.

__global__ __launch_bounds__(256) void k_gather(const float* __restrict__ Hc,
                                                const int* __restrict__ csr_src,
                                                const int* __restrict__ row_ptr,
                                                const float* __restrict__ dinv,
                                                const float* __restrict__ b,
                                                float* __restrict__ O, int N) {
    int chunk = blockIdx.x & (CHUNKS - 1);
    int node = (blockIdx.x >> 3) * 256 + threadIdx.x;
    if (node >= N) return;
    size_t NC = (size_t)N * CW;
    const float* Hk = Hc + (size_t)chunk * NC;

    int s0 = __builtin_nontemporal_load(row_ptr + node);
    int s1 = __builtin_nontemporal_load(row_ptr + node + 1);
    float di = dinv[node];
    float d2 = di * di;

    const float* bc = b + chunk * CW;
    const float* hn = Hk + (size_t)node * CW;
    float4 a0 = *reinterpret_cast<const float4*>(bc);
    float4 a1 = *reinterpret_cast<const float4*>(bc + 4);
    float4 a2 = *reinterpret_cast<const float4*>(bc + 8);
    {
        float4 h0 = *reinterpret_cast<const float4*>(hn);
        float4 h1 = *reinterpret_cast<const float4*>(hn + 4);
        float4 h2 = *reinterpret_cast<const float4*>(hn + 8);
        a0.x = fmaf(h0.x, d2, a0.x); a0.y = fmaf(h0.y, d2, a0.y);
        a0.z = fmaf(h0.z, d2, a0.z); a0.w = fmaf(h0.w, d2, a0.w);
        a1.x = fmaf(h1.x, d2, a1.x); a1.y = fmaf(h1.y, d2, a1.y);
        a1.z = fmaf(h1.z, d2, a1.z); a1.w = fmaf(h1.w, d2, a1.w);
        a2.x = fmaf(h2.x, d2, a2.x); a2.y = fmaf(h2.y, d2, a2.y);
        a2.z = fmaf(h2.z, d2, a2.z); a2.w = fmaf(h2.w, d2, a2.w);
    }

    int e = s0;
    for (; e + 1 < s1; e += 2) {
        int sA = __builtin_nontemporal_load(csr_src + e);
        int sB = __builtin_nontemporal_load(csr_src + e + 1);
        float wA = dinv[sA] * di;
        float wB = dinv[sB] * di;
        const float* hA = Hk + (size_t)sA * CW;
        const float* hB = Hk + (size_t)sB * CW;
        float4 A0 = *reinterpret_cast<const float4*>(hA);
        float4 A1 = *reinterpret_cast<const float4*>(hA + 4);
        float4 A2 = *reinterpret_cast<const float4*>(hA + 8);
        float4 B0 = *reinterpret_cast<const float4*>(hB);
        float4 B1 = *reinterpret_cast<const float4*>(hB + 4);
        float4 B2 = *reinterpret_cast<const float4*>(hB + 8);
        a0.x = fmaf(A0.x, wA, a0.x); a0.y = fmaf(A0.y, wA, a0.y);
        a0.z = fmaf(A0.z, wA, a0.z); a0.w = fmaf(A0.w, wA, a0.w);
        a1.x = fmaf(A1.x, wA, a1.x); a1.y = fmaf(A1.y, wA, a1.y);
        a1.z = fmaf(A1.z, wA, a1.z); a1.w = fmaf(A1.w, wA, a1.w);
        a2.x = fmaf(A2.x, wA, a2.x); a2.y = fmaf(A2.y, wA, a2.y);
        a2.z = fmaf(A2.z, wA, a2.z); a2.w = fmaf(A2.w, wA, a2.w);
        a0.x = fmaf(B0.x, wB, a0.x); a0.y = fmaf(B0.y, wB, a0.y);
        a0.z = fmaf(B0.z, wB, a0.z); a0.w = fmaf(B0.w, wB, a0.w);
        a1.x = fmaf(B1.x, wB, a1.x); a1.y = fmaf(B1.y, wB, a1.y);
        a1.z = fmaf(B1.z, wB, a1.z); a1.w = fmaf(B1.w, wB, a1.w);
        a2.x = fmaf(B2.x, wB, a2.x); a2.y = fmaf(B2.y, wB, a2.y);
        a2.z = fmaf(B2.z, wB, a2.z); a2.w = fmaf(B2.w, wB, a2.w);
    }
    if (e < s1) {
        int sA = __builtin_nontemporal_load(csr_src + e);
        float wA = dinv[sA] * di;
        const float* hA = Hk + (size_t)sA * CW;
        float4 A0 = *reinterpret_cast<const float4*>(hA);
        float4 A1 = *reinterpret_cast<const float4*>(hA + 4);
        float4 A2 = *reinterpret_cast<const float4*>(hA + 8);
        a0.x = fmaf(A0.x, wA, a0.x); a0.y = fmaf(A0.y, wA, a0.y);
        a0.z = fmaf(A0.z, wA, a0.z); a0.w = fmaf(A0.w, wA, a0.w);
        a1.x = fmaf(A1.x, wA, a1.x); a1.y = fmaf(A1.y, wA, a1.y);
        a1.z = fmaf(A1.z, wA, a1.z); a1.w = fmaf(A1.w, wA, a1.w);
        a2.x = fmaf(A2.x, wA, a2.x); a2.y = fmaf(A2.y, wA, a2.y);
        a2.z = fmaf(A2.z, wA, a2.z); a2.w = fmaf(A2.w, wA, a2.w);
    }

    float* o = O + (size_t)node * F + chunk * CW;
    f32x4 v0 = {a0.x, a0.y, a0.z, a0.w};
    f32x4 v1 = {a1.x, a1.y, a1.z, a1.w};
    f32x4 v2 = {a2.x, a2.y, a2.z, a2.w};
    __builtin_nontemporal_store(v0, (f32x4*)o);
    __builtin_nontemporal_store(v1, (f32x4*)(o + 4));
    __builtin_nontemporal_store(v2, (f32x4*)(o + 8));
}

// ================= fallback (atomic-scatter path, row-major) =================

__global__ void k_init_deg(float* __restrict__ deg, int N) {
    int i = blockIdx.x * blockDim.x + threadIdx.x;
    if (i < N) deg[i] = 1.0f;
}
__global__ void k_count(const int* __restrict__ dst, float* __restrict__ deg, int E) {
    int e = blockIdx.x * blockDim.x + threadIdx.x;
    if (e < E) atomicAdd(&deg[dst[e]], 1.0f);
}
__global__ void k_rsqrt(float* __restrict__ deg, int N) {
    int i = blockIdx.x * blockDim.x + threadIdx.x;
    if (i < N) deg[i] = rsqrtf(deg[i]);
}
__global__ void k_init_out(const float* __restrict__ H, const float* __restrict__ dinv,
                           const float* __restrict__ b, float* __restrict__ O, int N) {
    int idx = blockIdx.x * blockDim.x + threadIdx.x;
    if (idx >= N * F) return;
    int i = idx / F, f = idx % F;
    float di = dinv[i];
    O[idx] = fmaf(H[idx], di * di, b[f]);
}
__global__ __launch_bounds__(256) void k_scatter(const float* __restrict__ H,
                                                 const int* __restrict__ src,
                                                 const int* __restrict__ dst,
                                                 const float* __restrict__ dinv,
                                                 float* __restrict__ O, int E) {
    int t = blockIdx.x * 256 + threadIdx.x;
    int e = t >> 5;
    if (e >= E) return;
    int lf = t & 31;
    int s = src[e], d = dst[e];
    float nrm = dinv[s] * dinv[d];
    const float* hs = H + (size_t)s * F;
    float* od = O + (size_t)d * F;
#pragma unroll
    for (int j = 0; j < 3; ++j) atomicAdd(&od[lf + 32 * j], hs[lf + 32 * j] * nrm);
}

// ================= launch =================

extern "C" void kernel_launch(void* const* d_in, const int* in_sizes, int n_in,
                              void* d_out, int out_size, void* d_ws, size_t ws_size,
                              hipStream_t stream) {
    const float* x  = (const float*)d_in[0];
    const float* W1 = (const float*)d_in[1];
    const float* b1 = (const float*)d_in[2];
    const float* W2 = (const float*)d_in[3];
    const float* b2 = (const float*)d_in[4];
    const float* W3 = (const float*)d_in[5];
    const float* b3 = (const float*)d_in[6];
    const int*   ei = (const int*)d_in[7];

    const int N = in_sizes[0] / F;
    const int E = in_sizes[7] / 2;
    const int* src = ei;
    const int* dst = ei + E;
    const size_t NF = (size_t)N * F;

    const int thr = 256;
    dim3 blk(thr);
    int gN  = (N + thr - 1) / thr;
    int gE  = (E + thr - 1) / thr;
    int gDen = (N + 63) / 64;
    int gGat = CHUNKS * ((N + thr - 1) / thr);
    int nScanB = (N + SCAN_B - 1) / SCAN_B;

    // ---- workspace layout (CSR path) ----
    float* dinv    = (float*)d_ws;                 // N
    int*   row_ptr = (int*)(dinv + N);             // N+1
    int*   csr_src = row_ptr + N + 1;              // E
    float* A       = (float*)(csr_src + E);        // N*F (chunk-major Hc)
    float* B       = A + NF;                       // N*F (row-major)
    int* hist   = (int*)A;                         // temps (dead before use of A/B)
    int* incl   = hist + N;
    int* cursor = (int*)B;
    int* bsum   = cursor + N;

    size_t need = ((size_t)N + (N + 1) + (size_t)E + 2 * NF) * 4;
    float* out = (float*)d_out;

    if (ws_size >= need && nScanB <= SCAN_B) {
        // ---- CSR build (once; reused by all 3 layers) ----
        k_zero_i<<<gN, blk, 0, stream>>>(hist, N);
        k_hist<<<gE, blk, 0, stream>>>(dst, hist, E);
        k_scan1<<<nScanB, dim3(SCAN_B), 0, stream>>>(hist, incl, bsum, N);
        k_scan2<<<1, dim3(SCAN_B), 0, stream>>>(bsum, nScanB);
        k_scan3<<<gN, blk, 0, stream>>>(incl, hist, bsum, row_ptr, cursor, N, E);
        k_dinv<<<gN, blk, 0, stream>>>(hist, dinv, N);   // before A is overwritten
        k_place<<<gE, blk, 0, stream>>>(src, dst, cursor, csr_src, E);

        // ---- layer 1 ----
        k_dense<false, true><<<gDen, blk, 0, stream>>>(x, W1, A, N);
        k_gather<<<gGat, blk, 0, stream>>>(A, csr_src, row_ptr, dinv, b1, B, N);
        // ---- layer 2 ----
        k_dense<true, true><<<gDen, blk, 0, stream>>>(B, W2, A, N);
        k_gather<<<gGat, blk, 0, stream>>>(A, csr_src, row_ptr, dinv, b2, B, N);
        // ---- layer 3 ----
        k_dense<true, true><<<gDen, blk, 0, stream>>>(B, W3, A, N);
        k_gather<<<gGat, blk, 0, stream>>>(A, csr_src, row_ptr, dinv, b3, out, N);
    } else {
        // ---- fallback: atomic-scatter path ----
        float* fdinv = (float*)d_ws;
        float* fA = fdinv + N;
        float* fB = fA + NF;
        int gNF = (int)((NF + thr - 1) / thr);
        int gSc = (int)(((size_t)E * 32 + thr - 1) / thr);
        k_init_deg<<<gN, blk, 0, stream>>>(fdinv, N);
        k_count<<<gE, blk, 0, stream>>>(dst, fdinv, E);
        k_rsqrt<<<gN, blk, 0, stream>>>(fdinv, N);
        k_dense<false, false><<<gDen, blk, 0, stream>>>(x, W1, fA, N);
        k_init_out<<<gNF, blk, 0, stream>>>(fA, fdinv, b1, fB, N);
        k_scatter<<<gSc, blk, 0, stream>>>(fA, src, dst, fdinv, fB, E);
        k_dense<true, false><<<gDen, blk, 0, stream>>>(fB, W2, fA, N);
        k_init_out<<<gNF, blk, 0, stream>>>(fA, fdinv, b2, out, N);
        k_scatter<<<gSc, blk, 0, stream>>>(fA, src, dst, fdinv, out, E);
        k_dense<true, false><<<gDen, blk, 0, stream>>>(out, W3, fA, N);
        k_init_out<<<gNF, blk, 0, stream>>>(fA, fdinv, b3, fB, N);
        k_scatter<<<gSc, blk, 0, stream>>>(fA, src, dst, fdinv, fB, E);
        hipMemcpyAsync(out, fB, NF * sizeof(float), hipMemcpyDeviceToDevice, stream);
    }
}

// Round 5
// 583.131 us; speedup vs baseline: 1.0641x; 1.0641x over previous
//
#include <hip/hip_runtime.h>

#define F 96
#define SCAN_B 1024
#define CHUNKS 8
#define CW 12        // F / CHUNKS
#define NPB 21       // nodes per gather block (21*12 = 252 active lanes)

// Wt[c][k] stored XOR-swizzled so column-of-W float4 reads spread across banks.
#define WT_IDX(c, k) ((c) * 96 + (((k) ^ (((c) & 7) << 2))))

// ================= CSR build =================

__global__ void k_zero_i(int* __restrict__ p, int n) {
    int i = blockIdx.x * blockDim.x + threadIdx.x;
    if (i < n) p[i] = 0;
}

__global__ void k_hist(const int* __restrict__ dst, int* __restrict__ hist, int E) {
    int e = blockIdx.x * blockDim.x + threadIdx.x;
    if (e < E) atomicAdd(&hist[dst[e]], 1);
}

__global__ void k_dinv(const int* __restrict__ hist, float* __restrict__ dinv, int N) {
    int i = blockIdx.x * blockDim.x + threadIdx.x;
    if (i < N) dinv[i] = rsqrtf((float)hist[i] + 1.0f);  // +1 self-loop
}

__global__ __launch_bounds__(SCAN_B) void k_scan1(const int* __restrict__ hist,
                                                  int* __restrict__ incl,
                                                  int* __restrict__ bsum, int N) {
    __shared__ int s[SCAN_B];
    int i = blockIdx.x * SCAN_B + threadIdx.x;
    int v = (i < N) ? hist[i] : 0;
    s[threadIdx.x] = v;
    __syncthreads();
    for (int off = 1; off < SCAN_B; off <<= 1) {
        int add = (threadIdx.x >= off) ? s[threadIdx.x - off] : 0;
        __syncthreads();
        s[threadIdx.x] += add;
        __syncthreads();
    }
    if (i < N) incl[i] = s[threadIdx.x];
    if (threadIdx.x == SCAN_B - 1) bsum[blockIdx.x] = s[SCAN_B - 1];
}

__global__ __launch_bounds__(SCAN_B) void k_scan2(int* __restrict__ bsum, int nb) {
    __shared__ int s[SCAN_B];
    int v = (threadIdx.x < nb) ? bsum[threadIdx.x] : 0;
    s[threadIdx.x] = v;
    __syncthreads();
    for (int off = 1; off < SCAN_B; off <<= 1) {
        int add = (threadIdx.x >= off) ? s[threadIdx.x - off] : 0;
        __syncthreads();
        s[threadIdx.x] += add;
        __syncthreads();
    }
    if (threadIdx.x < nb) bsum[threadIdx.x] = s[threadIdx.x] - v;  // exclusive
}

__global__ void k_scan3(const int* __restrict__ incl, const int* __restrict__ hist,
                        const int* __restrict__ bsum, int* __restrict__ row_ptr,
                        int* __restrict__ cursor, int N, int E) {
    int i = blockIdx.x * blockDim.x + threadIdx.x;
    if (i < N) {
        int start = incl[i] - hist[i] + bsum[i / SCAN_B];
        row_ptr[i] = start;
        cursor[i] = start;
    }
    if (i == 0) row_ptr[N] = E;
}

__global__ void k_place(const int* __restrict__ src, const int* __restrict__ dst,
                        int* __restrict__ cursor, int* __restrict__ csr_src, int E) {
    int e = blockIdx.x * blockDim.x + threadIdx.x;
    if (e >= E) return;
    int pos = atomicAdd(&cursor[dst[e]], 1);
    csr_src[pos] = src[e];
}

// ================= dense: H = (relu?)(X) @ W =================
// CHIN/COUT select row-major [N][96] vs chunk-major [8][N][12] layouts.
// LDS: Wt (transposed W, XOR-swizzled) + XsOs union buffer [64][100]
// (X tile during k-loop, output tile during epilogue).

template <bool RELU_IN, bool CHIN_CHUNK, bool COUT_CHUNK>
__global__ __launch_bounds__(256) void k_dense(const float* __restrict__ X,
                                               const float* __restrict__ W,
                                               float* __restrict__ H, int N) {
    __shared__ float Wt[96 * 96];
    __shared__ float XsOs[64][100];
    int t = threadIdx.x;
    const size_t NC = (size_t)N * CW;

    for (int i = t; i < F * F; i += 256) {
        int k = i / F, c = i % F;
        Wt[WT_IDX(c, k)] = W[i];
    }
    int row0 = blockIdx.x * 64;

    // ---- stage input tile ----
    if (CHIN_CHUNK) {
        for (int q = t; q < 1536; q += 256) {
            int f = q / 192, rem = q % 192;
            int node = rem / 3, o = (rem % 3) * 4;
            int gr = row0 + node;
            float4 v = make_float4(0.f, 0.f, 0.f, 0.f);
            if (gr < N) {
                v = *reinterpret_cast<const float4*>(X + (size_t)f * NC + (size_t)gr * CW + o);
                if (RELU_IN) {
                    v.x = fmaxf(v.x, 0.f); v.y = fmaxf(v.y, 0.f);
                    v.z = fmaxf(v.z, 0.f); v.w = fmaxf(v.w, 0.f);
                }
            }
            *reinterpret_cast<float4*>(&XsOs[node][f * CW + o]) = v;
        }
    } else {
        for (int q = t; q < 1536; q += 256) {
            int node = q / 24, o = (q % 24) * 4;
            int gr = row0 + node;
            float4 v = make_float4(0.f, 0.f, 0.f, 0.f);
            if (gr < N) {
                v = *reinterpret_cast<const float4*>(X + (size_t)gr * F + o);
                if (RELU_IN) {
                    v.x = fmaxf(v.x, 0.f); v.y = fmaxf(v.y, 0.f);
                    v.z = fmaxf(v.z, 0.f); v.w = fmaxf(v.w, 0.f);
                }
            }
            *reinterpret_cast<float4*>(&XsOs[node][o]) = v;
        }
    }
    __syncthreads();

    // ---- compute ----
    int c2 = t & 31;
    int rg = t >> 5;
    float acc[8][3];
#pragma unroll
    for (int j = 0; j < 8; ++j) { acc[j][0] = 0.f; acc[j][1] = 0.f; acc[j][2] = 0.f; }

    for (int k4 = 0; k4 < F; k4 += 4) {
        float4 w0 = *reinterpret_cast<const float4*>(&Wt[WT_IDX(c2, k4)]);
        float4 w1 = *reinterpret_cast<const float4*>(&Wt[WT_IDX(c2 + 32, k4)]);
        float4 w2 = *reinterpret_cast<const float4*>(&Wt[WT_IDX(c2 + 64, k4)]);
#pragma unroll
        for (int j = 0; j < 8; ++j) {
            float4 xv = *reinterpret_cast<const float4*>(&XsOs[rg + 8 * j][k4]);
            acc[j][0] = fmaf(xv.x, w0.x, acc[j][0]);
            acc[j][1] = fmaf(xv.x, w1.x, acc[j][1]);
            acc[j][2] = fmaf(xv.x, w2.x, acc[j][2]);
            acc[j][0] = fmaf(xv.y, w0.y, acc[j][0]);
            acc[j][1] = fmaf(xv.y, w1.y, acc[j][1]);
            acc[j][2] = fmaf(xv.y, w2.y, acc[j][2]);
            acc[j][0] = fmaf(xv.z, w0.z, acc[j][0]);
            acc[j][1] = fmaf(xv.z, w1.z, acc[j][1]);
            acc[j][2] = fmaf(xv.z, w2.z, acc[j][2]);
            acc[j][0] = fmaf(xv.w, w0.w, acc[j][0]);
            acc[j][1] = fmaf(xv.w, w1.w, acc[j][1]);
            acc[j][2] = fmaf(xv.w, w2.w, acc[j][2]);
        }
    }
    __syncthreads();  // all k-loop reads done before overwriting XsOs

    // ---- stage output tile to LDS ----
#pragma unroll
    for (int j = 0; j < 8; ++j) {
        XsOs[rg + 8 * j][c2]      = acc[j][0];
        XsOs[rg + 8 * j][c2 + 32] = acc[j][1];
        XsOs[rg + 8 * j][c2 + 64] = acc[j][2];
    }
    __syncthreads();

    // ---- coalesced store ----
    if (COUT_CHUNK) {
        for (int q = t; q < 1536; q += 256) {
            int f = q / 192, rem = q % 192;
            int node = rem / 3, o = (rem % 3) * 4;
            int gr = row0 + node;
            if (gr < N) {
                *reinterpret_cast<float4*>(H + (size_t)f * NC + (size_t)gr * CW + o) =
                    *reinterpret_cast<const float4*>(&XsOs[node][f * CW + o]);
            }
        }
    } else {
        for (int q = t; q < 1536; q += 256) {
            int node = q / 24, o = (q % 24) * 4;
            int gr = row0 + node;
            if (gr < N) {
                *reinterpret_cast<float4*>(H + (size_t)gr * F + o) =
                    *reinterpret_cast<const float4*>(&XsOs[node][o]);
            }
        }
    }
}

// ================= gather aggregation (chunk x XCD partitioned) =================
// chunk = blockIdx&7 pins each feature chunk to one XCD (round-robin dispatch);
// per-XCD hot set = 2.4 MB Hc chunk + dinv -> L2-resident.
// 12 lanes per node (lane = feature in chunk), 21 nodes per block.

template <bool OUT_ROW>
__global__ __launch_bounds__(256) void k_gather(const float* __restrict__ Hc,
                                                const int* __restrict__ csr_src,
                                                const int* __restrict__ row_ptr,
                                                const float* __restrict__ dinv,
                                                const float* __restrict__ b,
                                                float* __restrict__ O, int N) {
    int t = threadIdx.x;
    if (t >= NPB * CW) return;
    int chunk = blockIdx.x & (CHUNKS - 1);
    int node = (blockIdx.x >> 3) * NPB + t / CW;
    if (node >= N) return;
    int lf = t % CW;
    size_t NC = (size_t)N * CW;
    const float* Hk = Hc + (size_t)chunk * NC;

    int s0 = __builtin_nontemporal_load(row_ptr + node);
    int s1 = __builtin_nontemporal_load(row_ptr + node + 1);
    float di = dinv[node];
    float acc = fmaf(Hk[(size_t)node * CW + lf], di * di, b[chunk * CW + lf]);

    int e = s0;
    for (; e + 3 < s1; e += 4) {
        int sA = __builtin_nontemporal_load(csr_src + e);
        int sB = __builtin_nontemporal_load(csr_src + e + 1);
        int sC = __builtin_nontemporal_load(csr_src + e + 2);
        int sD = __builtin_nontemporal_load(csr_src + e + 3);
        float wA = dinv[sA] * di, wB = dinv[sB] * di;
        float wC = dinv[sC] * di, wD = dinv[sD] * di;
        float hA = Hk[(size_t)sA * CW + lf];
        float hB = Hk[(size_t)sB * CW + lf];
        float hC = Hk[(size_t)sC * CW + lf];
        float hD = Hk[(size_t)sD * CW + lf];
        acc = fmaf(hA, wA, acc);
        acc = fmaf(hB, wB, acc);
        acc = fmaf(hC, wC, acc);
        acc = fmaf(hD, wD, acc);
    }
    for (; e < s1; ++e) {
        int sA = __builtin_nontemporal_load(csr_src + e);
        float wA = dinv[sA] * di;
        acc = fmaf(Hk[(size_t)sA * CW + lf], wA, acc);
    }

    if (OUT_ROW)
        O[(size_t)node * F + chunk * CW + lf] = acc;
    else
        O[(size_t)chunk * NC + (size_t)node * CW + lf] = acc;
}

// ================= fallback (atomic-scatter path, row-major) =================

__global__ void k_init_deg(float* __restrict__ deg, int N) {
    int i = blockIdx.x * blockDim.x + threadIdx.x;
    if (i < N) deg[i] = 1.0f;
}
__global__ void k_count(const int* __restrict__ dst, float* __restrict__ deg, int E) {
    int e = blockIdx.x * blockDim.x + threadIdx.x;
    if (e < E) atomicAdd(&deg[dst[e]], 1.0f);
}
__global__ void k_rsqrt(float* __restrict__ deg, int N) {
    int i = blockIdx.x * blockDim.x + threadIdx.x;
    if (i < N) deg[i] = rsqrtf(deg[i]);
}
__global__ void k_init_out(const float* __restrict__ H, const float* __restrict__ dinv,
                           const float* __restrict__ b, float* __restrict__ O, int N) {
    int idx = blockIdx.x * blockDim.x + threadIdx.x;
    if (idx >= N * F) return;
    int i = idx / F, f = idx % F;
    float di = dinv[i];
    O[idx] = fmaf(H[idx], di * di, b[f]);
}
__global__ __launch_bounds__(256) void k_scatter(const float* __restrict__ H,
                                                 const int* __restrict__ src,
                                                 const int* __restrict__ dst,
                                                 const float* __restrict__ dinv,
                                                 float* __restrict__ O, int E) {
    int t = blockIdx.x * 256 + threadIdx.x;
    int e = t >> 5;
    if (e >= E) return;
    int lf = t & 31;
    int s = src[e], d = dst[e];
    float nrm = dinv[s] * dinv[d];
    const float* hs = H + (size_t)s * F;
    float* od = O + (size_t)d * F;
#pragma unroll
    for (int j = 0; j < 3; ++j) atomicAdd(&od[lf + 32 * j], hs[lf + 32 * j] * nrm);
}

// ================= launch =================

extern "C" void kernel_launch(void* const* d_in, const int* in_sizes, int n_in,
                              void* d_out, int out_size, void* d_ws, size_t ws_size,
                              hipStream_t stream) {
    const float* x  = (const float*)d_in[0];
    const float* W1 = (const float*)d_in[1];
    const float* b1 = (const float*)d_in[2];
    const float* W2 = (const float*)d_in[3];
    const float* b2 = (const float*)d_in[4];
    const float* W3 = (const float*)d_in[5];
    const float* b3 = (const float*)d_in[6];
    const int*   ei = (const int*)d_in[7];

    const int N = in_sizes[0] / F;
    const int E = in_sizes[7] / 2;
    const int* src = ei;
    const int* dst = ei + E;
    const size_t NF = (size_t)N * F;

    const int thr = 256;
    dim3 blk(thr);
    int gN  = (N + thr - 1) / thr;
    int gE  = (E + thr - 1) / thr;
    int gDen = (N + 63) / 64;
    int gGat = CHUNKS * ((N + NPB - 1) / NPB);
    int nScanB = (N + SCAN_B - 1) / SCAN_B;

    // ---- workspace layout (CSR path) ----
    float* dinv    = (float*)d_ws;                 // N
    int*   row_ptr = (int*)(dinv + N);             // N+1
    int*   csr_src = row_ptr + N + 1;              // E
    float* A       = (float*)(csr_src + E);        // N*F (chunk-major)
    float* B       = A + NF;                       // N*F (chunk-major)
    int* hist   = (int*)A;                         // temps (dead before A/B use)
    int* incl   = hist + N;
    int* cursor = (int*)B;
    int* bsum   = cursor + N;

    size_t need = ((size_t)N + (N + 1) + (size_t)E + 2 * NF) * 4;
    float* out = (float*)d_out;

    if (ws_size >= need && nScanB <= SCAN_B) {
        // ---- CSR build (once; reused by all 3 layers) ----
        k_zero_i<<<gN, blk, 0, stream>>>(hist, N);
        k_hist<<<gE, blk, 0, stream>>>(dst, hist, E);
        k_scan1<<<nScanB, dim3(SCAN_B), 0, stream>>>(hist, incl, bsum, N);
        k_scan2<<<1, dim3(SCAN_B), 0, stream>>>(bsum, nScanB);
        k_scan3<<<gN, blk, 0, stream>>>(incl, hist, bsum, row_ptr, cursor, N, E);
        k_dinv<<<gN, blk, 0, stream>>>(hist, dinv, N);   // before A is overwritten
        k_place<<<gE, blk, 0, stream>>>(src, dst, cursor, csr_src, E);

        // ---- layer 1 ----
        k_dense<false, false, true><<<gDen, blk, 0, stream>>>(x, W1, A, N);
        k_gather<false><<<gGat, blk, 0, stream>>>(A, csr_src, row_ptr, dinv, b1, B, N);
        // ---- layer 2 ----
        k_dense<true, true, true><<<gDen, blk, 0, stream>>>(B, W2, A, N);
        k_gather<false><<<gGat, blk, 0, stream>>>(A, csr_src, row_ptr, dinv, b2, B, N);
        // ---- layer 3 ----
        k_dense<true, true, true><<<gDen, blk, 0, stream>>>(B, W3, A, N);
        k_gather<true><<<gGat, blk, 0, stream>>>(A, csr_src, row_ptr, dinv, b3, out, N);
    } else {
        // ---- fallback: atomic-scatter path ----
        float* fdinv = (float*)d_ws;
        float* fA = fdinv + N;
        float* fB = fA + NF;
        int gNF = (int)((NF + thr - 1) / thr);
        int gSc = (int)(((size_t)E * 32 + thr - 1) / thr);
        k_init_deg<<<gN, blk, 0, stream>>>(fdinv, N);
        k_count<<<gE, blk, 0, stream>>>(dst, fdinv, E);
        k_rsqrt<<<gN, blk, 0, stream>>>(fdinv, N);
        k_dense<false, false, false><<<gDen, blk, 0, stream>>>(x, W1, fA, N);
        k_init_out<<<gNF, blk, 0, stream>>>(fA, fdinv, b1, fB, N);
        k_scatter<<<gSc, blk, 0, stream>>>(fA, src, dst, fdinv, fB, E);
        k_dense<true, false, false><<<gDen, blk, 0, stream>>>(fB, W2, fA, N);
        k_init_out<<<gNF, blk, 0, stream>>>(fA, fdinv, b2, out, N);
        k_scatter<<<gSc, blk, 0, stream>>>(fA, src, dst, fdinv, out, E);
        k_dense<true, false, false><<<gDen, blk, 0, stream>>>(out, W3, fA, N);
        k_init_out<<<gNF, blk, 0, stream>>>(fA, fdinv, b3, fB, N);
        k_scatter<<<gSc, blk, 0, stream>>>(fA, src, dst, fdinv, fB, E);
        hipMemcpyAsync(out, fB, NF * sizeof(float), hipMemcpyDeviceToDevice, stream);
    }
}